// Round 18
// baseline (16.282 us; speedup 1.0000x reference)
//
#include <hip/hip_runtime.h>
#include <hip/hip_bf16.h>

// Shapes: x,gn (8,128,64) f32; fb (1,128,32768) f32; resonance (64,128) f32.
// out (8,1,32768) f32.
// r[b,c,f] = sum_rr softmax(x+gn)[b,c,rr] * res[rr,f]
// out[b,s] = (1/128) * sum_c lerp(r[b,c,:], s) * fb[c,s]
//
// Fused v8. Lessons: R16 (13.6 best) = dedup'd p2; R17 regression = barriers
// cost more than DS savings; replays run warm (fb L2-resident) so this is
// pure issue/latency tuning. v8:
//  - SEG=256 -> 512 blocks x 256 thr = 2 blocks/CU: block A's p1 (VALU/exp)
//    overlaps block B's p2 (VMEM/DS) on the same CU.
//  - 3 staged frames (lo in {seg-1, seg}); il = duo>>6 wave-uniform exactly.
//  - p2 refactor: dot-lo/dot-hi accumulators (no per-band sub/t-chain),
//    4 independent float2 accs, pk_fma-shaped; lerp once at the end.
//  - bp-major: bi = bp*128+seg, bi%8 = seg%8 -> same-seg blocks on one XCD.

#define BATCH 8
#define BANDS 128
#define RES 64
#define NF 128
#define NS 32768
#define SEG 256
#define NSEG (NS / SEG)    // 128
#define NBP 4              // batch pairs
#define NTHR 256

__global__ __launch_bounds__(NTHR) void fused(const float* __restrict__ x,
                                              const float* __restrict__ gn,
                                              const float* __restrict__ fb,
                                              const float* __restrict__ res,
                                              float* __restrict__ out) {
    const int bi  = blockIdx.x;       // 0..511, bp-major
    const int bp  = bi >> 7;          // 0..3
    const int seg = bi & 127;         // 0..127
    const int tid = threadIdx.x;      // 0..255

    __shared__ float resc[3][RES];    // staged res columns [frame j][rr]
    __shared__ float r4[3][256];      // r per staged frame, row = bl*128+c

    const int fbase = seg - 1;        // lo in {seg-1, seg}; il = lo-fbase in {0,1}

    if (tid < 3 * RES) {
        const int j = tid >> 6, rr = tid & 63;
        const int f = min(max(fbase + j, 0), NF - 1);
        resc[j][rr] = res[rr * NF + f];
    }
    __syncthreads();

    // ---- hoist this lane's resc slice (16 elems x 3 frames) to registers ----
    const int e0 = (tid & 3) * 16;
    float4 cr[3][4];
    #pragma unroll
    for (int f = 0; f < 3; ++f)
        #pragma unroll
        for (int j = 0; j < 4; ++j)
            cr[f][j] = *(const float4*)&resc[f][e0 + 4 * j];

    // ---- Phase 1: 256 rows (2 batches x 128 bands), 4 passes, 4 lanes/row ----
    const int q = tid >> 2;           // row-in-pass 0..63
    #pragma unroll
    for (int p = 0; p < 4; ++p) {
        const int row = p * 64 + q;   // 0..255
        const int bl  = row >> 7;
        const int c   = row & 127;
        const int bc  = (2 * bp + bl) * BANDS + c;

        const float4* __restrict__ xp = (const float4*)(x  + bc * RES + e0);
        const float4* __restrict__ gp = (const float4*)(gn + bc * RES + e0);

        float s = 0.f, d0 = 0.f, d1 = 0.f, d2 = 0.f;
        #pragma unroll
        for (int j = 0; j < 4; ++j) {
            const float4 a = xp[j];
            const float4 b = gp[j];
            const float ex = __expf(a.x + b.x);
            const float ey = __expf(a.y + b.y);
            const float ez = __expf(a.z + b.z);
            const float ew = __expf(a.w + b.w);
            s += (ex + ey) + (ez + ew);
            d0 = fmaf(ex, cr[0][j].x, fmaf(ey, cr[0][j].y, fmaf(ez, cr[0][j].z, fmaf(ew, cr[0][j].w, d0))));
            d1 = fmaf(ex, cr[1][j].x, fmaf(ey, cr[1][j].y, fmaf(ez, cr[1][j].z, fmaf(ew, cr[1][j].w, d1))));
            d2 = fmaf(ex, cr[2][j].x, fmaf(ey, cr[2][j].y, fmaf(ez, cr[2][j].z, fmaf(ew, cr[2][j].w, d2))));
        }
        s  += __shfl_xor(s, 1);  s  += __shfl_xor(s, 2);
        d0 += __shfl_xor(d0, 1); d0 += __shfl_xor(d0, 2);
        d1 += __shfl_xor(d1, 1); d1 += __shfl_xor(d1, 2);
        d2 += __shfl_xor(d2, 1); d2 += __shfl_xor(d2, 2);

        if ((tid & 3) == 0) {
            const float inv = 1.0f / s;
            r4[0][row] = d0 * inv;
            r4[1][row] = d1 * inv;
            r4[2][row] = d2 * inv;
        }
    }
    __syncthreads();

    // ---- Phase 2: threads 0..127 = sample duos; both batches per thread ----
    if (tid >= 128) return;

    const int d  = tid;               // 0..127
    const int s0 = seg * SEG + 2 * d;

    float p0 = ((float)s0 + 0.5f) * (1.0f / 256.0f) - 0.5f;
    float p1 = ((float)s0 + 1.5f) * (1.0f / 256.0f) - 0.5f;
    p0 = fminf(fmaxf(p0, 0.0f), (float)(NF - 1));
    p1 = fminf(fmaxf(p1, 0.0f), (float)(NF - 1));
    const int lo = (int)floorf(p0);   // wave-uniform: il = d>>6
    const int il = lo - fbase;        // 0 or 1
    const float w0 = p0 - (float)lo;
    const float w1 = p1 - (float)lo;

    const float* __restrict__ rlp = &r4[il][0];
    const float* __restrict__ rhp = &r4[il + 1][0];

    float2 lo0 = {0.f, 0.f}, hi0 = {0.f, 0.f};
    float2 lo1 = {0.f, 0.f}, hi1 = {0.f, 0.f};

    #pragma unroll 8
    for (int cc = 0; cc < BANDS / 4; ++cc) {
        const float4 a0 = *(const float4*)&rlp[4 * cc];         // batch0 lo
        const float4 b0 = *(const float4*)&rhp[4 * cc];         // batch0 hi
        const float4 a1 = *(const float4*)&rlp[128 + 4 * cc];   // batch1 lo
        const float4 b1 = *(const float4*)&rhp[128 + 4 * cc];   // batch1 hi
        const int band0 = 4 * cc;

        const float2 f0 = *(const float2*)&fb[(band0 + 0) * NS + s0];
        const float2 f1 = *(const float2*)&fb[(band0 + 1) * NS + s0];
        const float2 f2 = *(const float2*)&fb[(band0 + 2) * NS + s0];
        const float2 f3 = *(const float2*)&fb[(band0 + 3) * NS + s0];

        lo0.x = fmaf(f0.x, a0.x, lo0.x); lo0.y = fmaf(f0.y, a0.x, lo0.y);
        hi0.x = fmaf(f0.x, b0.x, hi0.x); hi0.y = fmaf(f0.y, b0.x, hi0.y);
        lo1.x = fmaf(f0.x, a1.x, lo1.x); lo1.y = fmaf(f0.y, a1.x, lo1.y);
        hi1.x = fmaf(f0.x, b1.x, hi1.x); hi1.y = fmaf(f0.y, b1.x, hi1.y);

        lo0.x = fmaf(f1.x, a0.y, lo0.x); lo0.y = fmaf(f1.y, a0.y, lo0.y);
        hi0.x = fmaf(f1.x, b0.y, hi0.x); hi0.y = fmaf(f1.y, b0.y, hi0.y);
        lo1.x = fmaf(f1.x, a1.y, lo1.x); lo1.y = fmaf(f1.y, a1.y, lo1.y);
        hi1.x = fmaf(f1.x, b1.y, hi1.x); hi1.y = fmaf(f1.y, b1.y, hi1.y);

        lo0.x = fmaf(f2.x, a0.z, lo0.x); lo0.y = fmaf(f2.y, a0.z, lo0.y);
        hi0.x = fmaf(f2.x, b0.z, hi0.x); hi0.y = fmaf(f2.y, b0.z, hi0.y);
        lo1.x = fmaf(f2.x, a1.z, lo1.x); lo1.y = fmaf(f2.y, a1.z, lo1.y);
        hi1.x = fmaf(f2.x, b1.z, hi1.x); hi1.y = fmaf(f2.y, b1.z, hi1.y);

        lo0.x = fmaf(f3.x, a0.w, lo0.x); lo0.y = fmaf(f3.y, a0.w, lo0.y);
        hi0.x = fmaf(f3.x, b0.w, hi0.x); hi0.y = fmaf(f3.y, b0.w, hi0.y);
        lo1.x = fmaf(f3.x, a1.w, lo1.x); lo1.y = fmaf(f3.y, a1.w, lo1.y);
        hi1.x = fmaf(f3.x, b1.w, hi1.x); hi1.y = fmaf(f3.y, b1.w, hi1.y);
    }

    const float sc = 1.0f / (float)BANDS;
    float2 o0, o1;
    o0.x = fmaf(w0, hi0.x - lo0.x, lo0.x) * sc;
    o0.y = fmaf(w1, hi0.y - lo0.y, lo0.y) * sc;
    o1.x = fmaf(w0, hi1.x - lo1.x, lo1.x) * sc;
    o1.y = fmaf(w1, hi1.y - lo1.y, lo1.y) * sc;
    *(float2*)&out[(2 * bp + 0) * NS + s0] = o0;
    *(float2*)&out[(2 * bp + 1) * NS + s0] = o1;
}

extern "C" void kernel_launch(void* const* d_in, const int* in_sizes, int n_in,
                              void* d_out, int out_size, void* d_ws, size_t ws_size,
                              hipStream_t stream) {
    const float* x   = (const float*)d_in[0];
    const float* gn  = (const float*)d_in[1];
    const float* fb  = (const float*)d_in[2];
    const float* res = (const float*)d_in[3];
    float* out = (float*)d_out;

    fused<<<NBP * NSEG, NTHR, 0, stream>>>(x, gn, fb, res, out);
}

// Round 19
// 13.377 us; speedup vs baseline: 1.2172x; 1.2172x over previous
//
#include <hip/hip_runtime.h>
#include <hip/hip_bf16.h>

// Shapes: x,gn (8,128,64) f32; fb (1,128,32768) f32; resonance (64,128) f32.
// out (8,1,32768) f32.
// r[b,c,f] = sum_rr softmax(x+gn)[b,c,rr] * res[rr,f]
// out[b,s] = (1/128) * sum_c lerp(r[b,c,:], s) * fb[c,s]
//
// Fused v9 = R16 (13.6us best) with p2 re-divided to halve the DS stream.
// R16 p2 accounting: 4 waves x 128 ds_read_b128 = 512 instrs x ~12cyc on the
// per-CU LDS pipe ~= 2.6us — the dominant term. v9: thread = (1 batch x 4
// samples) instead of (2 batches x 2 samples): DS 64/thread (halved), same
// 4 active waves, fb as float4 (same instr count, 2x bytes but L2-served).
// R17/R18 lessons honored: no extra barriers, block count stays 256 (p1
// redundancy is per-block), p1 untouched.

#define BATCH 8
#define BANDS 128
#define RES 64
#define NF 128
#define NS 32768
#define SEG 512
#define NSEG (NS / SEG)    // 64
#define NBP 4              // batch pairs
#define NTHR 512

__global__ __launch_bounds__(NTHR) void fused(const float* __restrict__ x,
                                              const float* __restrict__ gn,
                                              const float* __restrict__ fb,
                                              const float* __restrict__ res,
                                              float* __restrict__ out) {
    const int bi  = blockIdx.x;       // 0..255, bp-major
    const int bp  = bi >> 6;          // 0..3
    const int seg = bi & 63;          // 0..63
    const int tid = threadIdx.x;      // 0..511

    __shared__ float resc[4][RES];    // staged res columns [frame j][rr]
    __shared__ float r4[4][256];      // r per staged frame, row = bl*128+c

    const int fbase = 2 * seg - 1;    // lo in {2seg-1..2seg+1}; il=lo-fbase in 0..2

    if (tid < 4 * RES) {
        const int rr = tid >> 2, j = tid & 3;
        const int f = min(max(fbase + j, 0), NF - 1);
        resc[j][rr] = res[rr * NF + f];
    }
    __syncthreads();

    // ---- hoist this lane's resc slice (16 elems x 4 frames) to registers ----
    const int e0 = (tid & 3) * 16;
    float4 cr[4][4];
    #pragma unroll
    for (int f = 0; f < 4; ++f)
        #pragma unroll
        for (int j = 0; j < 4; ++j)
            cr[f][j] = *(const float4*)&resc[f][e0 + 4 * j];

    // ---- Phase 1: 256 rows (2 batches x 128 bands), 2 passes, 4 lanes/row ----
    const int q = tid >> 2;
    #pragma unroll
    for (int p = 0; p < 2; ++p) {
        const int row = p * 128 + q;
        const int bl  = row >> 7;
        const int c   = row & 127;
        const int bc  = (2 * bp + bl) * BANDS + c;

        const float4* __restrict__ xp = (const float4*)(x  + bc * RES + e0);
        const float4* __restrict__ gp = (const float4*)(gn + bc * RES + e0);

        float s = 0.f, d0 = 0.f, d1 = 0.f, d2 = 0.f, d3 = 0.f;
        #pragma unroll
        for (int j = 0; j < 4; ++j) {
            const float4 a = xp[j];
            const float4 b = gp[j];
            const float ex = __expf(a.x + b.x);
            const float ey = __expf(a.y + b.y);
            const float ez = __expf(a.z + b.z);
            const float ew = __expf(a.w + b.w);
            s += (ex + ey) + (ez + ew);
            d0 = fmaf(ex, cr[0][j].x, fmaf(ey, cr[0][j].y, fmaf(ez, cr[0][j].z, fmaf(ew, cr[0][j].w, d0))));
            d1 = fmaf(ex, cr[1][j].x, fmaf(ey, cr[1][j].y, fmaf(ez, cr[1][j].z, fmaf(ew, cr[1][j].w, d1))));
            d2 = fmaf(ex, cr[2][j].x, fmaf(ey, cr[2][j].y, fmaf(ez, cr[2][j].z, fmaf(ew, cr[2][j].w, d2))));
            d3 = fmaf(ex, cr[3][j].x, fmaf(ey, cr[3][j].y, fmaf(ez, cr[3][j].z, fmaf(ew, cr[3][j].w, d3))));
        }
        s  += __shfl_xor(s, 1);  s  += __shfl_xor(s, 2);
        d0 += __shfl_xor(d0, 1); d0 += __shfl_xor(d0, 2);
        d1 += __shfl_xor(d1, 1); d1 += __shfl_xor(d1, 2);
        d2 += __shfl_xor(d2, 1); d2 += __shfl_xor(d2, 2);
        d3 += __shfl_xor(d3, 1); d3 += __shfl_xor(d3, 2);

        if ((tid & 3) == 0) {
            const float inv = 1.0f / s;
            r4[0][row] = d0 * inv;
            r4[1][row] = d1 * inv;
            r4[2][row] = d2 * inv;
            r4[3][row] = d3 * inv;
        }
    }
    __syncthreads();

    // ---- Phase 2: threads 0..255; thread = (batch bl, quad of 4 samples) ----
    if (tid >= 256) return;

    const int bl = tid >> 7;          // 0..1
    const int qd = tid & 127;         // quad id 0..127
    const int s0 = seg * SEG + 4 * qd;

    float w0, w1, w2, w3;
    int il;
    {
        float pv0 = ((float)(s0 + 0) + 0.5f) * (1.0f / 256.0f) - 0.5f;
        float pv1 = ((float)(s0 + 1) + 0.5f) * (1.0f / 256.0f) - 0.5f;
        float pv2 = ((float)(s0 + 2) + 0.5f) * (1.0f / 256.0f) - 0.5f;
        float pv3 = ((float)(s0 + 3) + 0.5f) * (1.0f / 256.0f) - 0.5f;
        pv0 = fminf(fmaxf(pv0, 0.0f), (float)(NF - 1));
        pv1 = fminf(fmaxf(pv1, 0.0f), (float)(NF - 1));
        pv2 = fminf(fmaxf(pv2, 0.0f), (float)(NF - 1));
        pv3 = fminf(fmaxf(pv3, 0.0f), (float)(NF - 1));
        const int lo = (int)floorf(pv0);   // quad-uniform (crossings at in-seg
        il = lo - fbase;                   //  offsets 127.5/383.5, between quads)
        w0 = pv0 - (float)lo; w1 = pv1 - (float)lo;
        w2 = pv2 - (float)lo; w3 = pv3 - (float)lo;
    }

    const float* __restrict__ rlp = &r4[il][bl * BANDS];
    const float* __restrict__ rhp = &r4[il + 1][bl * BANDS];

    float4 aclo = {0.f, 0.f, 0.f, 0.f};
    float4 achi = {0.f, 0.f, 0.f, 0.f};

    #pragma unroll 4
    for (int cc = 0; cc < BANDS / 4; ++cc) {
        const int cb = 4 * cc;
        const float4 f0 = *(const float4*)&fb[(cb + 0) * NS + s0];
        const float4 f1 = *(const float4*)&fb[(cb + 1) * NS + s0];
        const float4 f2 = *(const float4*)&fb[(cb + 2) * NS + s0];
        const float4 f3 = *(const float4*)&fb[(cb + 3) * NS + s0];

        const float4 rl4 = *(const float4*)&rlp[cb];   // <=2 addrs/wave: free
        const float4 rh4 = *(const float4*)&rhp[cb];

        aclo.x = fmaf(f0.x, rl4.x, aclo.x); achi.x = fmaf(f0.x, rh4.x, achi.x);
        aclo.y = fmaf(f0.y, rl4.x, aclo.y); achi.y = fmaf(f0.y, rh4.x, achi.y);
        aclo.z = fmaf(f0.z, rl4.x, aclo.z); achi.z = fmaf(f0.z, rh4.x, achi.z);
        aclo.w = fmaf(f0.w, rl4.x, aclo.w); achi.w = fmaf(f0.w, rh4.x, achi.w);

        aclo.x = fmaf(f1.x, rl4.y, aclo.x); achi.x = fmaf(f1.x, rh4.y, achi.x);
        aclo.y = fmaf(f1.y, rl4.y, aclo.y); achi.y = fmaf(f1.y, rh4.y, achi.y);
        aclo.z = fmaf(f1.z, rl4.y, aclo.z); achi.z = fmaf(f1.z, rh4.y, achi.z);
        aclo.w = fmaf(f1.w, rl4.y, aclo.w); achi.w = fmaf(f1.w, rh4.y, achi.w);

        aclo.x = fmaf(f2.x, rl4.z, aclo.x); achi.x = fmaf(f2.x, rh4.z, achi.x);
        aclo.y = fmaf(f2.y, rl4.z, aclo.y); achi.y = fmaf(f2.y, rh4.z, achi.y);
        aclo.z = fmaf(f2.z, rl4.z, aclo.z); achi.z = fmaf(f2.z, rh4.z, achi.z);
        aclo.w = fmaf(f2.w, rl4.z, aclo.w); achi.w = fmaf(f2.w, rh4.z, achi.w);

        aclo.x = fmaf(f3.x, rl4.w, aclo.x); achi.x = fmaf(f3.x, rh4.w, achi.x);
        aclo.y = fmaf(f3.y, rl4.w, aclo.y); achi.y = fmaf(f3.y, rh4.w, achi.y);
        aclo.z = fmaf(f3.z, rl4.w, aclo.z); achi.z = fmaf(f3.z, rh4.w, achi.z);
        aclo.w = fmaf(f3.w, rl4.w, aclo.w); achi.w = fmaf(f3.w, rh4.w, achi.w);
    }

    const float sc = 1.0f / (float)BANDS;
    float4 o;
    o.x = fmaf(w0, achi.x - aclo.x, aclo.x) * sc;
    o.y = fmaf(w1, achi.y - aclo.y, aclo.y) * sc;
    o.z = fmaf(w2, achi.z - aclo.z, aclo.z) * sc;
    o.w = fmaf(w3, achi.w - aclo.w, aclo.w) * sc;
    *(float4*)&out[(2 * bp + bl) * NS + s0] = o;
}

extern "C" void kernel_launch(void* const* d_in, const int* in_sizes, int n_in,
                              void* d_out, int out_size, void* d_ws, size_t ws_size,
                              hipStream_t stream) {
    const float* x   = (const float*)d_in[0];
    const float* gn  = (const float*)d_in[1];
    const float* fb  = (const float*)d_in[2];
    const float* res = (const float*)d_in[3];
    float* out = (float*)d_out;

    fused<<<NBP * NSEG, NTHR, 0, stream>>>(x, gn, fb, res, out);
}